// Round 11
// baseline (301.446 us; speedup 1.0000x reference)
//
#include <hip/hip_runtime.h>
#include <hip/hip_bf16.h>

#define NN   8192
#define DIN  512
#define DOUT 256

typedef __attribute__((ext_vector_type(8)))  short s16x8;   // 8 bf16 (A/B frag)
typedef __attribute__((ext_vector_type(16))) float f32x16;  // 32x32 C/D frag

static __device__ __forceinline__ unsigned short f2bf(float f) {
    union { float f; unsigned u; } v; v.f = f;
    unsigned r = v.u + 0x7fffu + ((v.u >> 16) & 1u);   // RNE
    return (unsigned short)(r >> 16);
}

// ---------------- Kernel 1: Wh = feat@W (fp32 regs) -> Bpk (packed B-frags), src/dst --
// Bpk layout: uint4 index (ct*512 + kt)*64 + lane, lane = lhi*32 + l31 holding
// bf16 Wh[kt*16 + lhi*8 .. +8][ct*32 + l31]  — exactly the 32x32x16 B-fragment.
__global__ __launch_bounds__(256) void k_wh3(const float* __restrict__ feat,
                                             const float* __restrict__ W,
                                             const float* __restrict__ a,
                                             uint4* __restrict__ Bpk,
                                             float* __restrict__ src,
                                             float* __restrict__ dst) {
    __shared__ float lf[16 * DIN];                 // 32 KB
    __shared__ float red[2][4][16];
    const int tid = threadIdx.x;
    const int i0  = blockIdx.x * 16;               // 16 k-rows (of Wh) per block
    const int w   = tid >> 6, lane = tid & 63;

    const float4* fsrc = (const float4*)(feat + (size_t)i0 * DIN);
    float4* fdst = (float4*)lf;
    #pragma unroll
    for (int q = 0; q < 8; ++q) fdst[tid + q * 256] = fsrc[tid + q * 256];
    __syncthreads();

    const int c = tid;                              // output channel (col)
    float outs[16];
    #pragma unroll
    for (int r = 0; r < 16; ++r) outs[r] = 0.f;

    for (int k = 0; k < DIN; k += 4) {
        float w0 = W[(k + 0) * DOUT + c];
        float w1 = W[(k + 1) * DOUT + c];
        float w2 = W[(k + 2) * DOUT + c];
        float w3 = W[(k + 3) * DOUT + c];
        #pragma unroll
        for (int r = 0; r < 16; ++r) {
            float4 f = *(const float4*)&lf[r * DIN + k];   // broadcast read
            outs[r] = fmaf(f.x, w0, fmaf(f.y, w1, fmaf(f.z, w2, fmaf(f.w, w3, outs[r]))));
        }
    }

    unsigned short tb[16];
    #pragma unroll
    for (int r = 0; r < 16; ++r) tb[r] = f2bf(outs[r]);
    // packed B-fragment write: ct = c>>5, l31 = c&31, kt = blockIdx.x
    const int ct = c >> 5, l31c = c & 31;
    Bpk[((size_t)ct * 512 + blockIdx.x) * 64 +  0 + l31c] = *(uint4*)&tb[0];
    Bpk[((size_t)ct * 512 + blockIdx.x) * 64 + 32 + l31c] = *(uint4*)&tb[8];

    // fused src/dst = Wh @ a halves (fp32, exact Wh from registers)
    const float as_ = a[c], ad_ = a[DOUT + c];
    #pragma unroll
    for (int r = 0; r < 16; ++r) {
        float s = outs[r] * as_;
        float d = outs[r] * ad_;
        #pragma unroll
        for (int off = 32; off; off >>= 1) {
            s += __shfl_xor(s, off);
            d += __shfl_xor(d, off);
        }
        if (lane == 0) { red[0][w][r] = s; red[1][w][r] = d; }
    }
    __syncthreads();
    if (tid < 16)
        src[i0 + tid] = red[0][0][tid] + red[0][1][tid] + red[0][2][tid] + red[0][3][tid];
    else if (tid < 32) {
        int r = tid - 16;
        dst[i0 + r] = red[1][0][r] + red[1][1][r] + red[1][2][r] + red[1][3][r];
    }
}

// ---------------- Kernel 1b: adj -> bitmask, LINEAR layout ---------------------------
__global__ __launch_bounds__(256) void k_mask(const int* __restrict__ adj,
                                              unsigned char* __restrict__ bits) {
    const int row = blockIdx.x;
    const int tid = threadIdx.x;
    const int* base = adj + (size_t)row * NN + tid * 32;
    unsigned int u = 0;
    #pragma unroll
    for (int j = 0; j < 8; ++j) {
        int4 v = *(const int4*)(base + j * 4);
        unsigned int b = (v.x > 0 ? 1u : 0u) | (v.y > 0 ? 2u : 0u) |
                         (v.z > 0 ? 4u : 0u) | (v.w > 0 ? 8u : 0u);
        u |= b << (j * 4);
    }
    *(unsigned int*)(bits + (size_t)row * 1024 + tid * 4) = u;
}

// ---------------- Kernel 2: masked-exp GEMM — ZERO barriers, ZERO LDS ----------------
// grid = 512: ks = bid&7 (k-split 8), rt = bid>>3. block = 256 = 4 fully independent
// waves; wave = 32 rows x 256 cols x 1024 k. A (P) built in-register in the 32x32x16
// A-frag layout (row = l31, k = lhi*8+j); B read as packed fragments from Bpk
// (coalesced 1KB/instr, L2-hot). P-build VALU (~400cy) covers B L2 latency. No
// inter-wave coupling anywhere: pure dataflow, compiler-managed waitcnts.
__global__ __launch_bounds__(256, 2) void k_attn10(const unsigned char* __restrict__ bits,
                                                   const uint4* __restrict__ Bpk,
                                                   const float* __restrict__ src,
                                                   const float* __restrict__ dstg,
                                                   float* __restrict__ denp,
                                                   float* __restrict__ part) {
    const int tid  = threadIdx.x;
    const int lane = tid & 63;
    const int wv   = tid >> 6;
    const int l31  = lane & 31, lhi = lane >> 5;
    const int lhi8 = lhi * 8;

    const int ks  = blockIdx.x & 7;
    const int rt  = blockIdx.x >> 3;
    const int ktg0 = ks * 64;                       // first 16-k tile of this chunk

    const int gr  = rt * 128 + wv * 32 + l31;       // this lane's P row
    const float si = src[gr];
    const unsigned char* bb = bits + (size_t)gr * 1024 + ks * 128;
    const float* dk = dstg + ks * 1024 + lhi8;

    f32x16 acc[8];
    #pragma unroll
    for (int ct = 0; ct < 8; ++ct)
        #pragma unroll
        for (int e = 0; e < 16; ++e) acc[ct][e] = 0.f;
    float den = 0.f;

    for (int t = 0; t < 64; ++t) {
        // B fragments (coalesced, L2-hot) — issued first, landed after P-build
        s16x8 bf[8];
        #pragma unroll
        for (int ct = 0; ct < 8; ++ct) {
            uint4 v = Bpk[((size_t)ct * 512 + ktg0 + t) * 64 + lane];
            bf[ct] = *(s16x8*)&v;
        }
        // P(t): 16 k for this lane's row; lane covers k = t*16 + lhi8 + (0..7)
        const unsigned int m16 = *(const unsigned short*)(bb + t * 2);
        const unsigned int m8  = (m16 >> lhi8) & 0xffu;
        float4 d0 = *(const float4*)(dk + t * 16);
        float4 d1 = *(const float4*)(dk + t * 16 + 4);
        const float df[8] = {d0.x, d0.y, d0.z, d0.w, d1.x, d1.y, d1.z, d1.w};
        s16x8 pa;
        #pragma unroll
        for (int jj = 0; jj < 8; ++jj) {
            float x = si + df[jj];
            x = fmaxf(x, 0.2f * x);                      // leaky_relu 0.2
            float p = (m8 >> jj) & 1u ? __expf(x) : 0.f; // bounded logits: no max-sub
            den += p;
            pa[jj] = (short)f2bf(p);
        }
        // 8 MFMAs, fully wave-local
        __builtin_amdgcn_s_setprio(1);
        #pragma unroll
        for (int ct = 0; ct < 8; ++ct)
            acc[ct] = __builtin_amdgcn_mfma_f32_32x32x16_bf16(pa, bf[ct], acc[ct], 0, 0, 0);
        __builtin_amdgcn_s_setprio(0);
    }

    // den: combine the two k-halves (lane ^ 32)
    den += __shfl_xor(den, 32);
    if (lhi == 0) denp[(size_t)ks * NN + gr] = den;

    // epilogue: C/D layout (m74/m101): col = lane&31, row = (e&3)+8*(e>>2)+4*lhi
    float* pp = part + (size_t)ks * (NN * DOUT);
    #pragma unroll
    for (int ct = 0; ct < 8; ++ct) {
        #pragma unroll
        for (int e = 0; e < 16; ++e) {
            const int row = rt * 128 + wv * 32 + (e & 3) + 8 * (e >> 2) + 4 * lhi;
            pp[(size_t)row * DOUT + ct * 32 + l31] = acc[ct][e];
        }
    }
}

// ---------------- Kernel 3: out = elu( (sum_ks num) / (sum_ks den) ) -----------------
__global__ __launch_bounds__(256) void k_finish3(const float* __restrict__ part,
                                                 const float* __restrict__ denp,
                                                 float* __restrict__ out) {
    const int idx = blockIdx.x * 256 + threadIdx.x;   // float4 units
    const int row = idx >> 6;                          // 64 float4 per row
    float den = 0.f;
    #pragma unroll
    for (int i = 0; i < 8; ++i) den += denp[(size_t)i * NN + row];
    float rv = den > 0.f ? 1.f / den : 0.f;
    const size_t st = (size_t)NN * DOUT / 4;
    const float4* p = (const float4*)part;
    float sx = 0.f, sy = 0.f, sz = 0.f, sw = 0.f;
    #pragma unroll
    for (int i = 0; i < 8; ++i) {
        float4 v = p[idx + i * st];
        sx += v.x; sy += v.y; sz += v.z; sw += v.w;
    }
    float4 s;
    s.x = sx * rv; s.y = sy * rv; s.z = sz * rv; s.w = sw * rv;
    s.x = s.x > 0.f ? s.x : expm1f(s.x);
    s.y = s.y > 0.f ? s.y : expm1f(s.y);
    s.z = s.z > 0.f ? s.z : expm1f(s.z);
    s.w = s.w > 0.f ? s.w : expm1f(s.w);
    ((float4*)out)[idx] = s;
}

extern "C" void kernel_launch(void* const* d_in, const int* in_sizes, int n_in,
                              void* d_out, int out_size, void* d_ws, size_t ws_size,
                              hipStream_t stream) {
    const float* feat = (const float*)d_in[0];
    const int*   adj  = (const int*)d_in[1];
    const float* W    = (const float*)d_in[2];
    const float* a    = (const float*)d_in[3];
    float* out = (float*)d_out;

    char* ws = (char*)d_ws;
    uint4*          Bpk  = (uint4*)ws;                        // 4 MB (packed B frags)
    float*          src  = (float*)(ws + 4194304);            // 32 KB
    float*          dst  = (float*)(ws + 4227072);            // 32 KB
    float*          denp = (float*)(ws + 4259840);            // 256 KB (8 x 32 KB)
    unsigned char*  bits = (unsigned char*)(ws + 4521984);    // 8 MB
    float*          part = (float*)(ws + 12910592);           // 64 MB (8 x 8 MB)

    k_mask  <<<8192, 256, 0, stream>>>(adj, bits);
    k_wh3   <<<512,  256, 0, stream>>>(feat, W, a, Bpk, src, dst);
    // ---- attribution instrument: attn launched TWICE (idempotent) ----
    // total = fixed + 2*attn  ->  attn duration becomes unambiguous next round.
    k_attn10<<<512,  256, 0, stream>>>(bits, Bpk, src, dst, denp, part);
    k_attn10<<<512,  256, 0, stream>>>(bits, Bpk, src, dst, denp, part);
    k_finish3<<<2048, 256, 0, stream>>>(part, denp, out);
}

// Round 12
// 222.530 us; speedup vs baseline: 1.3546x; 1.3546x over previous
//
#include <hip/hip_runtime.h>
#include <hip/hip_bf16.h>

#define NN   8192
#define DIN  512
#define DOUT 256

typedef __attribute__((ext_vector_type(8)))  short s16x8;   // 8 bf16 (A/B frag)
typedef __attribute__((ext_vector_type(16))) float f32x16;  // 32x32 C/D frag

static __device__ __forceinline__ unsigned short f2bf(float f) {
    union { float f; unsigned u; } v; v.f = f;
    unsigned r = v.u + 0x7fffu + ((v.u >> 16) & 1u);   // RNE
    return (unsigned short)(r >> 16);
}

// ---------------- Kernel 1: Wh = feat@W (fp32 regs) -> Bpk (packed B-frags), src/dst --
// Bpk layout (verified rounds 10-11): uint4 index (ct*512 + kt)*64 + lhi*32 + l31
// holds bf16 Wh[kt*16 + lhi*8 .. +8][ct*32 + l31] — the 32x32x16 B-fragment.
__global__ __launch_bounds__(256) void k_wh3(const float* __restrict__ feat,
                                             const float* __restrict__ W,
                                             const float* __restrict__ a,
                                             uint4* __restrict__ Bpk,
                                             float* __restrict__ src,
                                             float* __restrict__ dst) {
    __shared__ float lf[16 * DIN];                 // 32 KB
    __shared__ float red[2][4][16];
    const int tid = threadIdx.x;
    const int i0  = blockIdx.x * 16;               // 16 k-rows (of Wh) per block
    const int w   = tid >> 6, lane = tid & 63;

    const float4* fsrc = (const float4*)(feat + (size_t)i0 * DIN);
    float4* fdst = (float4*)lf;
    #pragma unroll
    for (int q = 0; q < 8; ++q) fdst[tid + q * 256] = fsrc[tid + q * 256];
    __syncthreads();

    const int c = tid;                              // output channel (col)
    float outs[16];
    #pragma unroll
    for (int r = 0; r < 16; ++r) outs[r] = 0.f;

    for (int k = 0; k < DIN; k += 4) {
        float w0 = W[(k + 0) * DOUT + c];
        float w1 = W[(k + 1) * DOUT + c];
        float w2 = W[(k + 2) * DOUT + c];
        float w3 = W[(k + 3) * DOUT + c];
        #pragma unroll
        for (int r = 0; r < 16; ++r) {
            float4 f = *(const float4*)&lf[r * DIN + k];   // broadcast read
            outs[r] = fmaf(f.x, w0, fmaf(f.y, w1, fmaf(f.z, w2, fmaf(f.w, w3, outs[r]))));
        }
    }

    unsigned short tb[16];
    #pragma unroll
    for (int r = 0; r < 16; ++r) tb[r] = f2bf(outs[r]);
    const int ct = c >> 5, l31c = c & 31;
    Bpk[((size_t)ct * 512 + blockIdx.x) * 64 +  0 + l31c] = *(uint4*)&tb[0];
    Bpk[((size_t)ct * 512 + blockIdx.x) * 64 + 32 + l31c] = *(uint4*)&tb[8];

    const float as_ = a[c], ad_ = a[DOUT + c];
    #pragma unroll
    for (int r = 0; r < 16; ++r) {
        float s = outs[r] * as_;
        float d = outs[r] * ad_;
        #pragma unroll
        for (int off = 32; off; off >>= 1) {
            s += __shfl_xor(s, off);
            d += __shfl_xor(d, off);
        }
        if (lane == 0) { red[0][w][r] = s; red[1][w][r] = d; }
    }
    __syncthreads();
    if (tid < 16)
        src[i0 + tid] = red[0][0][tid] + red[0][1][tid] + red[0][2][tid] + red[0][3][tid];
    else if (tid < 32) {
        int r = tid - 16;
        dst[i0 + r] = red[1][0][r] + red[1][1][r] + red[1][2][r] + red[1][3][r];
    }
}

// ---------------- Kernel 1b: adj -> bitmask, LINEAR layout ---------------------------
__global__ __launch_bounds__(256) void k_mask(const int* __restrict__ adj,
                                              unsigned char* __restrict__ bits) {
    const int row = blockIdx.x;
    const int tid = threadIdx.x;
    const int* base = adj + (size_t)row * NN + tid * 32;
    unsigned int u = 0;
    #pragma unroll
    for (int j = 0; j < 8; ++j) {
        int4 v = *(const int4*)(base + j * 4);
        unsigned int b = (v.x > 0 ? 1u : 0u) | (v.y > 0 ? 2u : 0u) |
                         (v.z > 0 ? 4u : 0u) | (v.w > 0 ? 8u : 0u);
        u |= b << (j * 4);
    }
    *(unsigned int*)(bits + (size_t)row * 1024 + tid * 4) = u;
}

// ---------------- Kernel 2: masked-exp GEMM — zero barriers, B reused 2x in-register --
// grid = 512: ks = bid&7 (k-split 8, XCD-aligned), rt = bid>>3 (64 tiles of 128 rows).
// block = 256 = 4 independent waves: wv&1 = row half (64 rows), wv>>1 = col half
// (128 cols). Wave: 2 A-frags (rows l31, l31+32) x 4 B-frags (CT) -> 8 MFMA/step;
// every B-frag feeds TWO MFMAs -> B L2 traffic halved vs round 11 (~0.5 GB).
// bits gather amortized: one u64 per row per 4 steps. P built 2x chip-wide (col halves).
__global__ __launch_bounds__(256, 2) void k_attn11(const unsigned char* __restrict__ bits,
                                                   const uint4* __restrict__ Bpk,
                                                   const float* __restrict__ src,
                                                   const float* __restrict__ dstg,
                                                   float* __restrict__ denp,
                                                   float* __restrict__ part) {
    const int tid  = threadIdx.x;
    const int lane = tid & 63;
    const int wv   = tid >> 6;
    const int l31  = lane & 31, lhi = lane >> 5;
    const int lhi8 = lhi * 8;
    const int rowg = wv & 1, colg = wv >> 1;

    const int ks   = blockIdx.x & 7;
    const int rt   = blockIdx.x >> 3;               // 0..63
    const int ktg0 = ks * 64;

    const int gr0 = rt * 128 + rowg * 64 + l31;     // A-frag 0 row
    const int gr1 = gr0 + 32;                       // A-frag 1 row
    const float si0 = src[gr0], si1 = src[gr1];
    const unsigned long long* bq0 =
        (const unsigned long long*)(bits + (size_t)gr0 * 1024 + ks * 128);
    const unsigned long long* bq1 =
        (const unsigned long long*)(bits + (size_t)gr1 * 1024 + ks * 128);
    const float* dk = dstg + ks * 1024 + lhi8;

    f32x16 acc[2][4];
    #pragma unroll
    for (int a = 0; a < 2; ++a)
        #pragma unroll
        for (int c = 0; c < 4; ++c)
            #pragma unroll
            for (int e = 0; e < 16; ++e) acc[a][c][e] = 0.f;
    float den0 = 0.f, den1 = 0.f;

    for (int tt = 0; tt < 16; ++tt) {
        const unsigned long long m0 = bq0[tt];      // masks for 4 steps, row gr0
        const unsigned long long m1 = bq1[tt];
        #pragma unroll
        for (int q = 0; q < 4; ++q) {
            const int t = tt * 4 + q;
            // B fragments (coalesced 1KB/instr, L2-hot, reused by both A-frags)
            s16x8 bf[4];
            #pragma unroll
            for (int c = 0; c < 4; ++c) {
                uint4 v = Bpk[((size_t)(colg * 4 + c) * 512 + ktg0 + t) * 64 + lane];
                bf[c] = *(s16x8*)&v;
            }
            float4 d0 = *(const float4*)(dk + t * 16);
            float4 d1 = *(const float4*)(dk + t * 16 + 4);
            const float df[8] = {d0.x, d0.y, d0.z, d0.w, d1.x, d1.y, d1.z, d1.w};
            const unsigned int m8_0 = (unsigned int)(m0 >> (q * 16 + lhi8)) & 0xffu;
            const unsigned int m8_1 = (unsigned int)(m1 >> (q * 16 + lhi8)) & 0xffu;
            s16x8 pa0, pa1;
            #pragma unroll
            for (int jj = 0; jj < 8; ++jj) {
                float x0 = si0 + df[jj];
                x0 = fmaxf(x0, 0.2f * x0);                       // leaky_relu 0.2
                float p0 = (m8_0 >> jj) & 1u ? __expf(x0) : 0.f; // bounded: no max-sub
                den0 += p0;
                pa0[jj] = (short)f2bf(p0);
                float x1 = si1 + df[jj];
                x1 = fmaxf(x1, 0.2f * x1);
                float p1 = (m8_1 >> jj) & 1u ? __expf(x1) : 0.f;
                den1 += p1;
                pa1[jj] = (short)f2bf(p1);
            }
            __builtin_amdgcn_s_setprio(1);
            #pragma unroll
            for (int c = 0; c < 4; ++c) {
                acc[0][c] = __builtin_amdgcn_mfma_f32_32x32x16_bf16(pa0, bf[c], acc[0][c], 0, 0, 0);
                acc[1][c] = __builtin_amdgcn_mfma_f32_32x32x16_bf16(pa1, bf[c], acc[1][c], 0, 0, 0);
            }
            __builtin_amdgcn_s_setprio(0);
        }
    }

    // den: combine the two k-halves (lane ^ 32 holds same row, other lhi)
    den0 += __shfl_xor(den0, 32);
    den1 += __shfl_xor(den1, 32);
    if (colg == 0 && lhi == 0) {
        denp[(size_t)ks * NN + gr0] = den0;
        denp[(size_t)ks * NN + gr1] = den1;
    }

    // epilogue: C/D layout (m74/m101): col = lane&31, row = (e&3)+8*(e>>2)+4*lhi
    float* pp = part + (size_t)ks * (NN * DOUT);
    #pragma unroll
    for (int a = 0; a < 2; ++a) {
        #pragma unroll
        for (int c = 0; c < 4; ++c) {
            #pragma unroll
            for (int e = 0; e < 16; ++e) {
                const int row = rt * 128 + rowg * 64 + a * 32 + (e & 3) + 8 * (e >> 2) + 4 * lhi;
                const int col = colg * 128 + c * 32 + l31;
                pp[(size_t)row * DOUT + col] = acc[a][c][e];
            }
        }
    }
}

// ---------------- Kernel 3: out = elu( (sum_ks num) / (sum_ks den) ) -----------------
__global__ __launch_bounds__(256) void k_finish3(const float* __restrict__ part,
                                                 const float* __restrict__ denp,
                                                 float* __restrict__ out) {
    const int idx = blockIdx.x * 256 + threadIdx.x;   // float4 units
    const int row = idx >> 6;                          // 64 float4 per row
    float den = 0.f;
    #pragma unroll
    for (int i = 0; i < 8; ++i) den += denp[(size_t)i * NN + row];
    float rv = den > 0.f ? 1.f / den : 0.f;
    const size_t st = (size_t)NN * DOUT / 4;
    const float4* p = (const float4*)part;
    float sx = 0.f, sy = 0.f, sz = 0.f, sw = 0.f;
    #pragma unroll
    for (int i = 0; i < 8; ++i) {
        float4 v = p[idx + i * st];
        sx += v.x; sy += v.y; sz += v.z; sw += v.w;
    }
    float4 s;
    s.x = sx * rv; s.y = sy * rv; s.z = sz * rv; s.w = sw * rv;
    s.x = s.x > 0.f ? s.x : expm1f(s.x);
    s.y = s.y > 0.f ? s.y : expm1f(s.y);
    s.z = s.z > 0.f ? s.z : expm1f(s.z);
    s.w = s.w > 0.f ? s.w : expm1f(s.w);
    ((float4*)out)[idx] = s;
}

extern "C" void kernel_launch(void* const* d_in, const int* in_sizes, int n_in,
                              void* d_out, int out_size, void* d_ws, size_t ws_size,
                              hipStream_t stream) {
    const float* feat = (const float*)d_in[0];
    const int*   adj  = (const int*)d_in[1];
    const float* W    = (const float*)d_in[2];
    const float* a    = (const float*)d_in[3];
    float* out = (float*)d_out;

    char* ws = (char*)d_ws;
    uint4*          Bpk  = (uint4*)ws;                        // 4 MB (packed B frags)
    float*          src  = (float*)(ws + 4194304);            // 32 KB
    float*          dst  = (float*)(ws + 4227072);            // 32 KB
    float*          denp = (float*)(ws + 4259840);            // 256 KB (8 x 32 KB)
    unsigned char*  bits = (unsigned char*)(ws + 4521984);    // 8 MB
    float*          part = (float*)(ws + 12910592);           // 64 MB (8 x 8 MB)

    k_mask   <<<8192, 256, 0, stream>>>(adj, bits);
    k_wh3    <<<512,  256, 0, stream>>>(feat, W, a, Bpk, src, dst);
    k_attn11 <<<512,  256, 0, stream>>>(bits, Bpk, src, dst, denp, part);
    k_finish3<<<2048, 256, 0, stream>>>(part, denp, out);
}